// Round 2
// baseline (615.483 us; speedup 1.0000x reference)
//
#include <hip/hip_runtime.h>

// SpaAggregator: out[b] = (mean_k id2feat[idx[b,k]]) @ W + bias
// B=16384, K=32, N=1e6, F=128, E=128. float32 in/out, int32 indices.
//
// mean commutes with the linear map: gather-average first, then a tiny GEMM.
// R0->R1 showed the gather is stuck at ~0.9 TB/s effective regardless of
// occupancy: the register-pipelined gather trades VGPRs against waves, so
// (waves x in-flight-loads) stays constant. This version uses
// global_load_lds DMA for the gather: outstanding loads cost ZERO VGPRs and
// the pipeline depth (8 x 1KB per wave) is enforced by explicit vmcnt
// waits, not compiler scheduling. 16 waves/CU x 8KB = 128KB in flight/CU
// by construction.
//
// Block = 256 threads (4 waves) handles 8 batch rows; wave w owns rows
// (2w, 2w+1):
//   phase 1: stage 256 neighbor indices -> LDS, then preload each wave's
//            32 per-lane indices to registers (static indexing only)
//   phase 2: DMA gather: each global_load_lds moves 2 rows (64 lanes x 16B
//            = 1KB, lanes 0-31 row 2w, lanes 32-63 row 2w+1) into a
//            per-wave 8-slot ring; rolling vmcnt(7) keeps 8 in flight;
//            accumulate each slot from LDS (contiguous b128, conflict-free)
//   phase 3: per-thread 1x4 output tile; A-row broadcast from LDS, W row
//            from L1/L2 (block-invariant, 64KB), fp32 store.

#define BATCH 16384
#define KNB   32
#define FDIM  128
#define EDIM  128
#define ROWS_PER_BLOCK 8
#define DEPTH 8        // DMA ring slots per wave (1KB each)
#define IDX_PITCH 33
#define A_PITCH  132

__global__ __launch_bounds__(256, 4)
void spa_agg_kernel(const float* __restrict__ id2feat,
                    const float* __restrict__ weight,
                    const float* __restrict__ bias,
                    const int* __restrict__ neigh_idx,
                    float* __restrict__ out) {
    __shared__ float4 stage[4][DEPTH][64];             // 32 KB DMA landing ring
    __shared__ float  sA[ROWS_PER_BLOCK * A_PITCH];    // ~4.2 KB
    __shared__ int    sIdx[ROWS_PER_BLOCK * IDX_PITCH];// ~1.1 KB

    const int tid  = threadIdx.x;
    const int lane = tid & 63;
    const int wv   = __builtin_amdgcn_readfirstlane(tid >> 6); // wave id, SGPR
    const int half = lane >> 5;    // 0: row 2w, 1: row 2w+1
    const int lr   = lane & 31;    // 16B chunk within the 512B row
    const int b0   = blockIdx.x * ROWS_PER_BLOCK;

    // ---- phase 1: stage neighbor indices (256 = blockDim, coalesced) ----
    sIdx[(tid >> 5) * IDX_PITCH + (tid & 31)] = neigh_idx[b0 * KNB + tid];
    __syncthreads();

    // preload this lane's 32 indices to registers (static indexing only)
    int myidx[KNB];
    {
        const int* ip = &sIdx[(2 * wv + half) * IDX_PITCH];
        #pragma unroll
        for (int k = 0; k < KNB; ++k) myidx[k] = ip[k];
    }

    // ---- phase 2: DMA gather + average ----
    float4* const mybuf = &stage[wv][0][0];      // wave-uniform LDS base
    const float* gsrc = id2feat + lr * 4;        // +16B chunk per lane

    #define WAITV(N) asm volatile("s_waitcnt vmcnt(" #N ")" ::: "memory")
    #define WAITL    asm volatile("s_waitcnt lgkmcnt(0)" ::: "memory")

    // prologue: fill the ring (8 x 1KB in flight)
    #pragma unroll
    for (int s = 0; s < DEPTH; ++s) {
        __builtin_amdgcn_global_load_lds(
            (const void*)(gsrc + (size_t)myidx[s] * FDIM),
            (void*)(mybuf + s * 64), 16, 0, 0);
    }

    float a0 = 0.f, a1 = 0.f, a2 = 0.f, a3 = 0.f;
    #define ACCUM(K) { const float4 v = mybuf[((K) & (DEPTH - 1)) * 64 + lane]; \
                       a0 += v.x; a1 += v.y; a2 += v.z; a3 += v.w; }

    // steady state: wait oldest slot, consume, refill same slot.
    // vmcnt retires in-order, so vmcnt(7) with 8 outstanding == slot k done.
    #pragma unroll
    for (int k = 0; k < KNB - DEPTH; ++k) {      // k = 0..23, fully unrolled
        WAITV(7);
        ACCUM(k);
        WAITL;  // ds_read retired before DMA may overwrite the slot
        __builtin_amdgcn_global_load_lds(
            (const void*)(gsrc + (size_t)myidx[k + DEPTH] * FDIM),
            (void*)(mybuf + (k & (DEPTH - 1)) * 64), 16, 0, 0);
    }
    // epilogue: drain 8 -> 0
    WAITV(7); ACCUM(24);
    WAITV(6); ACCUM(25);
    WAITV(5); ACCUM(26);
    WAITV(4); ACCUM(27);
    WAITV(3); ACCUM(28);
    WAITV(2); ACCUM(29);
    WAITV(1); ACCUM(30);
    WAITV(0); ACCUM(31);

    *(float4*)&sA[(2 * wv + half) * A_PITCH + lr * 4] =
        make_float4(a0 * (1.f / 32.f), a1 * (1.f / 32.f),
                    a2 * (1.f / 32.f), a3 * (1.f / 32.f));
    __syncthreads();

    // ---- phase 3: out[b0+lb][e0..e0+4) = sA[lb] . W[:, e0..e0+4) + bias ----
    {
        const int lb = tid >> 5;
        const int e0 = (tid & 31) * 4;
        float4 acc = *(const float4*)(bias + e0);
        const float* arow = &sA[lb * A_PITCH];
        #pragma unroll 8
        for (int f = 0; f < FDIM; ++f) {
            const float a  = arow[f];                          // LDS broadcast
            const float4 w4 = *(const float4*)(weight + (size_t)f * EDIM + e0);
            acc.x += a * w4.x; acc.y += a * w4.y;
            acc.z += a * w4.z; acc.w += a * w4.w;
        }
        *(float4*)(out + (size_t)(b0 + lb) * EDIM + e0) = acc;
    }
}

extern "C" void kernel_launch(void* const* d_in, const int* in_sizes, int n_in,
                              void* d_out, int out_size, void* d_ws, size_t ws_size,
                              hipStream_t stream) {
    const float* id2feat = (const float*)d_in[0];  // [N, F] fp32
    const float* weight  = (const float*)d_in[1];  // [F, E] fp32
    const float* bias    = (const float*)d_in[2];  // [E]    fp32
    const int*   neigh   = (const int*)d_in[3];    // [B, K] int32
    float*       outp    = (float*)d_out;          // [B, E] fp32

    dim3 grid(BATCH / ROWS_PER_BLOCK);  // 2048
    dim3 block(256);
    spa_agg_kernel<<<grid, block, 0, stream>>>(id2feat, weight, bias, neigh, outp);
}